// Round 1
// 6375.459 us; speedup vs baseline: 1.0617x; 1.0617x over previous
//
#include <hip/hip_runtime.h>
#include <hip/hip_fp16.h>

// Problem constants: B=8, F=48, S=64, D=512, NH=8, L=4, DFF=2048, M=64, PERIOD=30

// ---------------- f16 dot2 helpers ----------------
typedef _Float16 h2 __attribute__((ext_vector_type(2)));
__device__ inline h2 u2h(unsigned u){ union{unsigned u; h2 h;} c; c.u=u; return c.h; }
#if __has_builtin(__builtin_amdgcn_fdot2)
__device__ inline float FDOT2(h2 a, h2 b, float c){ return __builtin_amdgcn_fdot2(a, b, c, false); }
#else
__device__ inline float FDOT2(h2 a, h2 b, float c){
  return fmaf((float)a.y, (float)b.y, fmaf((float)a.x, (float)b.x, c));
}
#endif

__device__ inline float aload(const float* p){
  return __hip_atomic_load(p, __ATOMIC_RELAXED, __HIP_MEMORY_SCOPE_AGENT);
}
__device__ inline void astore(float* p, float v){
  __hip_atomic_store(p, v, __ATOMIC_RELAXED, __HIP_MEMORY_SCOPE_AGENT);
}

// dot of n (multiple of 8) f16 weights (contiguous row) with f16 x (LDS),
// fp32 accumulation via v_dot2_f32_f16, 4 independent chains for ILP.
__device__ inline float dot_f16(const ushort* wrow, const ushort* xh, int n){
  const uint4* w4 = (const uint4*)wrow;
  const uint4* x4 = (const uint4*)xh;
  float a0=0.f, a1=0.f, a2=0.f, a3=0.f;
  #pragma unroll 4
  for (int i=0; i<(n>>3); ++i){
    uint4 w = w4[i], x = x4[i];
    a0 = FDOT2(u2h(w.x), u2h(x.x), a0);
    a1 = FDOT2(u2h(w.y), u2h(x.y), a1);
    a2 = FDOT2(u2h(w.z), u2h(x.z), a2);
    a3 = FDOT2(u2h(w.w), u2h(x.w), a3);
  }
  return (a0+a1)+(a2+a3);
}
// dot of n (multiple of 4) fp32 weights with fp32 x, 4 accumulators
__device__ inline float dot_f32(const float* wrow, const float* x, int n){
  const float4* w4 = (const float4*)wrow;
  float a0=0.f, a1=0.f, a2=0.f, a3=0.f;
  #pragma unroll 4
  for (int i=0; i<(n>>2); ++i){
    float4 w = w4[i];
    const float* xp = x + i*4;
    a0 = fmaf(w.x, xp[0], a0); a1 = fmaf(w.y, xp[1], a1);
    a2 = fmaf(w.z, xp[2], a2); a3 = fmaf(w.w, xp[3], a3);
  }
  return (a0+a1)+(a2+a3);
}

// ---------------- transpose (src R x C -> dst C x R) ----------------
__global__ void k_transpose(const float* __restrict__ src, float* __restrict__ dst, int R, int C){
  __shared__ float tile[32][33];
  int cb = blockIdx.x*32, rb = blockIdx.y*32;
  int tx = threadIdx.x, ty = threadIdx.y;   // blockDim (32,8)
  for (int i=ty; i<32; i+=8) tile[i][tx] = src[(size_t)(rb+i)*C + cb+tx];
  __syncthreads();
  for (int i=ty; i<32; i+=8) dst[(size_t)(cb+i)*R + rb+tx] = tile[tx][i];
}

// cast fp32 -> f16 (same layout)
__global__ void k_casthf(const float* __restrict__ s, __half* __restrict__ d, int n){
  int i = blockIdx.x*256 + threadIdx.x;
  if (i < n) d[i] = __float2half(s[i]);
}

// ---------------- generic linear: C[r,o] = sum_d A[r,d]*Wt[d,o] + bias[o] ----------------
__global__ void k_linear(const float* __restrict__ A, int lda,
                         const float* __restrict__ Wt, int ldw,
                         const float* __restrict__ bias,
                         float* __restrict__ C, int ldc,
                         int O, int Din){
  __shared__ float xs[8*1024];
  __shared__ float red[4096];
  int tid = threadIdx.x;
  int r0 = blockIdx.y*8;
  for (int idx=tid; idx<8*Din; idx+=256){
    int ri = idx / Din, d = idx - ri*Din;
    xs[idx] = A[(size_t)(r0+ri)*lda + d];
  }
  __syncthreads();
  int op = tid & 63, kp = tid >> 6;
  int o = blockIdx.x*128 + op*2;
  int dq = Din >> 2;
  float a0[8] = {0,0,0,0,0,0,0,0}, a1[8] = {0,0,0,0,0,0,0,0};
  for (int d = kp*dq; d < kp*dq+dq; ++d){
    float2 w = *reinterpret_cast<const float2*>(&Wt[(size_t)d*ldw + o]);
    #pragma unroll
    for (int ri=0; ri<8; ++ri){ float x = xs[ri*Din+d]; a0[ri] += x*w.x; a1[ri] += x*w.y; }
  }
  #pragma unroll
  for (int ri=0; ri<8; ++ri){
    red[((kp*64+op)*8+ri)*2]   = a0[ri];
    red[((kp*64+op)*8+ri)*2+1] = a1[ri];
  }
  __syncthreads();
  for (int idx = tid; idx < 1024; idx += 256){
    int ri = idx >> 7, oc = idx & 127;
    int opp = oc >> 1, c = oc & 1;
    float v = red[((0*64+opp)*8+ri)*2 + c] + red[((1*64+opp)*8+ri)*2 + c]
            + red[((2*64+opp)*8+ri)*2 + c] + red[((3*64+opp)*8+ri)*2 + c];
    int oo = blockIdx.x*128 + oc;
    if (bias) v += bias[oo];
    C[(size_t)(r0+ri)*ldc + oo] = v;
  }
}

// ---------------- PE table ----------------
__global__ void k_pe(float* __restrict__ pe){
  int idx = blockIdx.x*256 + threadIdx.x;  // 48*512
  int t = idx >> 9, d = idx & 511;
  int p = t % 30;
  int i2 = d & ~1;
  float div = __expf(-(float)i2 * (9.210340371976184f/512.f));
  float ang = (float)p * div;
  pe[idx] = (d & 1) ? cosf(ang) : sinf(ang);
}

// ---------------- sel attention (nh=1) ----------------
__global__ void k_sel_attn(const float* __restrict__ qh, const float* __restrict__ kh,
                           const float* __restrict__ vh, float* __restrict__ o){
  int bf = blockIdx.x;           // b*48+f
  int b  = bf / 48;
  int tid = threadIdx.x;
  __shared__ float qs[512];
  __shared__ float ps[64];
  qs[tid] = qh[(size_t)bf*512 + tid];
  qs[tid+256] = qh[(size_t)bf*512 + tid + 256];
  __syncthreads();
  if (tid < 64){
    const float* kr = kh + (size_t)(b*64+tid)*512;
    float a = 0.f;
    for (int d=0; d<512; ++d) a += qs[d]*kr[d];
    ps[tid] = a * 0.04419417382415922f;
  }
  __syncthreads();
  if (tid == 0){
    float m = -1e30f;
    for (int j=0;j<64;++j) m = fmaxf(m, ps[j]);
    float s = 0.f;
    for (int j=0;j<64;++j){ float e = __expf(ps[j]-m); ps[j]=e; s+=e; }
    float iv = 1.f/s;
    for (int j=0;j<64;++j) ps[j] *= iv;
  }
  __syncthreads();
  float a0=0.f, a1=0.f;
  for (int j=0;j<64;++j){
    const float* vr = vh + (size_t)(b*64+j)*512;
    float pj = ps[j];
    a0 += pj*vr[tid]; a1 += pj*vr[tid+256];
  }
  o[(size_t)bf*512+tid] = a0;
  o[(size_t)bf*512+tid+256] = a1;
}

// ---------------- tiny glue ----------------
__global__ void k_cat_tail(const float* __restrict__ sel, float* __restrict__ cat){
  int idx = blockIdx.x*256 + threadIdx.x;  // 8*512
  int b = idx >> 9, d = idx & 511;
  cat[b*1024 + 512 + d] = sel[(size_t)(b*48)*512 + d];
}
__global__ void k_add_style(const float* __restrict__ embt, const float* __restrict__ style,
                            float* __restrict__ emb){
  int idx = blockIdx.x*256 + threadIdx.x;  // 8*512 -> emb slot t=0
  emb[idx] = embt[idx] + style[idx];
}

// ---------------- persistent decode kernel ----------------
// 128 blocks (<=256 CUs -> all co-resident), one batch per 16 WGs.
// role = (i&7)*2 + ((i>>3)&1): blocks sharing an XCD (i%8) share 2 roles,
// keeping the per-XCD weight working set ~3.4 MB (< 4 MB L2).
// Cross-WG data moves via agent-scope relaxed atomics; weights L2-resident.
struct DP {
  unsigned* fl;        // flags: [b][t][stage 0..8][role]
  float* z;            // [b][t][8 slots][512] accumulators (memset 0)
  float* emb;          // [t 0..48][b][512] (memset 0; slot0 from precompute)
  float* Vpriv;        // per-WG private V cache [wg][l][48][64]
  const ushort *Wqkv, *Wo, *Wf1, *Wf2;   // f16, original [out][in] layout
  const float *xa_c, *pe;
  const float *sa_in_b, *sa_out_b, *ff1_b, *ff2_b;
  const float *mmr_w, *mmr_b, *mm_w, *mm_b, *se_w, *se_b;
  const float *ln_g, *ln_b, *style, *sel;
  float* dec_out;
};

__launch_bounds__(256, 1)
__global__ void k_decode(DP p){
  const int tid = threadIdx.x;
  const int i = blockIdx.x;
  const int role = ((i & 7) << 1) | ((i >> 3) & 1);
  const int b = i >> 4;
  const int h = role >> 1, half = role & 1;
  const float slope = exp2f(-(float)(h+1));

  __shared__ float kc[4*48*65];   // K cache, fp32, pad 65 vs bank conflicts
  __shared__ float xs[512];       // fp32 x (tail only)
  __shared__ float red[512];
  __shared__ float qs[64], ps[64], d64[64];
  __shared__ float ns[512];
  __shared__ float lnred[8];
  __shared__ __align__(16) __half xhh[512];   // f16 x for dot2 paths
  __shared__ __align__(16) __half anh[64];    // f16 attn-out (head)
  __shared__ __align__(16) __half hsh[128];   // f16 FF hidden slice

  float* Vp = p.Vpriv + (size_t)i*4*48*64;
  unsigned* flb = p.fl + (size_t)b*48*9*16;
  float* zb = p.z + (size_t)b*48*8*512;

  auto wait16 = [&](int t, int s){
    unsigned* f = flb + (size_t)(t*9+s)*16;
    if (tid < 16){
      while (__hip_atomic_load(&f[tid], __ATOMIC_RELAXED, __HIP_MEMORY_SCOPE_AGENT) == 0u)
        __builtin_amdgcn_s_sleep(2);
    }
    __syncthreads();
  };
  auto post = [&](int t, int s){
    __syncthreads();   // all waves drain vmcnt (atomics complete) at barrier
    if (tid == 0)
      __hip_atomic_store(&flb[(size_t)(t*9+s)*16 + role], 1u,
                         __ATOMIC_RELEASE, __HIP_MEMORY_SCOPE_AGENT);
  };
  // LN over 512 (2 elems/thread). Results returned in r0/r1 (this thread's
  // elems tid and tid+256); optionally stored to fp32 out and/or f16 oh.
  auto lnorm = [&](float v0, float v1, const float* g, const float* bb,
                   float* out, __half* oh, float& r0, float& r1){
    float s = v0 + v1, q = v0*v0 + v1*v1;
    #pragma unroll
    for (int off=32; off>0; off>>=1){ s += __shfl_xor(s, off, 64); q += __shfl_xor(q, off, 64); }
    if ((tid & 63) == 0){ lnred[tid>>6] = s; lnred[4+(tid>>6)] = q; }
    __syncthreads();
    s = lnred[0]+lnred[1]+lnred[2]+lnred[3];
    q = lnred[4]+lnred[5]+lnred[6]+lnred[7];
    float mu = s * (1.f/512.f);
    float rs = rsqrtf(q*(1.f/512.f) - mu*mu + 1e-5f);
    r0 = (v0-mu)*rs*g[tid]     + bb[tid];
    r1 = (v1-mu)*rs*g[tid+256] + bb[tid+256];
    if (out){ out[tid] = r0; out[tid+256] = r1; }
    if (oh){ oh[tid] = __float2half(r0); oh[tid+256] = __float2half(r1); }
    __syncthreads();
  };

  for (int t=0; t<48; ++t){
    for (int l=0; l<4; ++l){
      // prefetch cross-attn constant for stage B (cold HBM) before any waiting
      const float* xac = p.xa_c + ((size_t)l*384 + b*48 + t)*512;
      float xa0 = xac[tid], xa1 = xac[tid+256];

      // ===== stage A: x prep + QKV (own head) + attention + O-partial =====
      float x0, x1;                // this thread's x (residual source)
      if (l == 0){
        float pe0 = p.pe[t*512+tid], pe1 = p.pe[t*512+tid+256]; // prefetch
        if (t > 0) wait16(t-1, 8);
        float e0 = aload(p.emb + ((size_t)t*8+b)*512 + tid);
        float e1 = aload(p.emb + ((size_t)t*8+b)*512 + tid + 256);
        x0 = e0 + pe0; x1 = e1 + pe1;
        xhh[tid]     = __float2half(x0);
        xhh[tid+256] = __float2half(x1);
        __syncthreads();
      } else {
        wait16(t, (l-1)*2+1);
        float* zs = zb + ((size_t)t*8 + (l-1)*2+1)*512;
        float z0 = aload(zs+tid), z1 = aload(zs+tid+256);
        lnorm(z0, z1, p.ln_g + ((l-1)*3+2)*512, p.ln_b + ((l-1)*3+2)*512,
              nullptr, xhh, x0, x1);
      }
      // QKV for head h: threads 0..63 q, 64..127 k, 128..191 v
      if (tid < 192){
        int sec = tid >> 6, dch = tid & 63;
        int row = sec*512 + h*64 + dch;
        float acc = dot_f16(p.Wqkv + ((size_t)l*1536+row)*512, (const ushort*)xhh, 512)
                  + p.sa_in_b[l*1536+row];
        if (sec == 0) qs[dch] = acc;
        else if (sec == 1) kc[(l*48+t)*65 + dch] = acc;
        else Vp[((size_t)l*48+t)*64 + dch] = acc;   // WG-private, plain cached
      }
      __syncthreads();
      // scores + softmax (wave 0)
      if (tid < 64){
        float sc = -1e30f;
        if (tid <= t){
          float a = 0.f;
          const float* kr = &kc[(l*48+tid)*65];
          #pragma unroll
          for (int d=0; d<64; ++d) a = fmaf(qs[d], kr[d], a);
          sc = a*0.125f - ((t-tid) >= 30 ? slope : 0.f);
        }
        float m = sc;
        #pragma unroll
        for (int off=32; off>0; off>>=1) m = fmaxf(m, __shfl_xor(m, off, 64));
        float e = (tid <= t) ? __expf(sc-m) : 0.f;
        float s = e;
        #pragma unroll
        for (int off=32; off>0; off>>=1) s += __shfl_xor(s, off, 64);
        ps[tid] = e / s;
      }
      __syncthreads();
      // PV: d = tid&63, j-quarter = tid>>6
      {
        int d = tid & 63, jq = tid >> 6;
        float a = 0.f;
        for (int j=jq*12; j<jq*12+12; ++j)
          if (j <= t) a = fmaf(ps[j], Vp[((size_t)l*48+j)*64 + d], a);
        red[tid] = a;
      }
      __syncthreads();
      if (tid < 64) anh[tid] = __float2half(red[tid]+red[64+tid]+red[128+tid]+red[192+tid]);
      __syncthreads();
      // O-partial over this head's 64 dims, out-half per `half`
      {
        int o = half*256 + tid;
        float acc = dot_f16(p.Wo + (((size_t)l*512+o)*512 + h*64), (const ushort*)anh, 64);
        if (h == 0) acc += (half ? x1 : x0) + p.sa_out_b[l*512+o];  // residual+bias once
        unsafeAtomicAdd(zb + ((size_t)t*8 + l*2)*512 + o, acc);
      }
      post(t, l*2);

      // ===== stage B: LN + cross-const + LN + FF1 slice + FF2 partial =====
      wait16(t, l*2);
      float r0, r1;   // u2 (this thread's elems) for FF2 residual
      {
        float* zs = zb + ((size_t)t*8 + l*2)*512;
        float z0 = aload(zs+tid), z1 = aload(zs+tid+256);
        float w0, w1;
        lnorm(z0, z1, p.ln_g + (l*3)*512, p.ln_b + (l*3)*512, nullptr, nullptr, w0, w1);
        float u0 = w0 + xa0, u1 = w1 + xa1;
        lnorm(u0, u1, p.ln_g + (l*3+1)*512, p.ln_b + (l*3+1)*512, nullptr, xhh, r0, r1);
      }
      {
        int oo = tid & 127, hh = tid >> 7;
        int row = role*128 + oo;
        red[tid] = dot_f16(p.Wf1 + ((size_t)l*2048+row)*512 + hh*256,
                           (const ushort*)xhh + hh*256, 256);
      }
      __syncthreads();
      if (tid < 128){
        float v = red[tid] + red[128+tid] + p.ff1_b[l*2048 + role*128 + tid];
        hsh[tid] = __float2half(fmaxf(v, 0.f));
      }
      __syncthreads();
      {
        float a0 = dot_f16(p.Wf2 + ((size_t)l*512+tid)*2048 + role*128, (const ushort*)hsh, 128);
        float a1 = dot_f16(p.Wf2 + ((size_t)l*512+tid+256)*2048 + role*128, (const ushort*)hsh, 128);
        if (role == 0){
          a0 += r0 + p.ff2_b[l*512+tid];
          a1 += r1 + p.ff2_b[l*512+tid+256];
        }
        float* zs = zb + ((size_t)t*8 + l*2+1)*512;
        unsafeAtomicAdd(zs+tid, a0);
        unsafeAtomicAdd(zs+tid+256, a1);
      }
      post(t, l*2+1);
    } // layers

    // ===== tail: LN + mmr -> dec_out, mm -> new, se -> next emb =====
    wait16(t, 7);
    {
      float* zs = zb + ((size_t)t*8 + 7)*512;
      float z0 = aload(zs+tid), z1 = aload(zs+tid+256);
      float w0, w1;
      lnorm(z0, z1, p.ln_g + 11*512, p.ln_b + 11*512, xs, nullptr, w0, w1);
    }
    {
      int o = tid & 63, kq = tid >> 6;
      red[tid] = dot_f32(p.mmr_w + (size_t)o*512 + kq*128, xs + kq*128, 128);
    }
    __syncthreads();
    if (tid < 64){
      float v = red[tid]+red[64+tid]+red[128+tid]+red[192+tid] + p.mmr_b[tid];
      d64[tid] = v;
      if (role == 0) p.dec_out[((size_t)b*48+t)*64 + tid] = v;
    }
    __syncthreads();
    {
      ns[tid]     = dot_f32(p.mm_w + (size_t)tid*64,       d64, 64) + p.mm_b[tid];
      ns[tid+256] = dot_f32(p.mm_w + (size_t)(tid+256)*64, d64, 64) + p.mm_b[tid+256];
    }
    __syncthreads();
    {
      int oo = tid & 31, part = tid >> 5;   // 8 parts x 128
      int o = role*32 + oo;
      float acc;
      if (part < 4)
        acc = dot_f32(p.se_w + (size_t)o*1024 + part*128, ns + part*128, 128);
      else
        acc = dot_f32(p.se_w + (size_t)o*1024 + part*128,
                      p.sel + ((size_t)b*48+t)*512 + (part-4)*128, 128);
      red[tid] = acc;
    }
    __syncthreads();
    if (tid < 32){
      float v = 0.f;
      #pragma unroll
      for (int k8=0; k8<8; ++k8) v += red[k8*32+tid];
      int o = role*32 + tid;
      v += p.se_b[o] + p.style[(size_t)b*512+o];
      astore(p.emb + ((size_t)(t+1)*8+b)*512 + o, v);
    }
    post(t, 8);
  } // t
}

// ---------------- host ----------------
extern "C" void kernel_launch(void* const* d_in, const int* in_sizes, int n_in,
                              void* d_out, int out_size, void* d_ws, size_t ws_size,
                              hipStream_t stream){
  (void)in_sizes; (void)n_in; (void)out_size; (void)ws_size;
  const float* content = (const float*)d_in[0];
  const float* style   = (const float*)d_in[1];
  const float* shid    = (const float*)d_in[2];
  const float* init_st = (const float*)d_in[3];
  const float* ca_in_w = (const float*)d_in[4];
  const float* ca_in_b = (const float*)d_in[5];
  const float* ca_out_w= (const float*)d_in[6];
  const float* ca_out_b= (const float*)d_in[7];
  const float* se_w    = (const float*)d_in[8];
  const float* se_b    = (const float*)d_in[9];
  const float* mm_w    = (const float*)d_in[10];
  const float* mm_b    = (const float*)d_in[11];
  const float* mmr_w   = (const float*)d_in[12];
  const float* mmr_b   = (const float*)d_in[13];
  const float* sa_in_w = (const float*)d_in[14];
  const float* sa_in_b = (const float*)d_in[15];
  const float* sa_out_w= (const float*)d_in[16];
  const float* sa_out_b= (const float*)d_in[17];
  const float* xa_in_w = (const float*)d_in[18];
  const float* xa_in_b = (const float*)d_in[19];
  const float* xa_out_w= (const float*)d_in[20];
  const float* xa_out_b= (const float*)d_in[21];
  const float* ff1_w   = (const float*)d_in[22];
  const float* ff1_b   = (const float*)d_in[23];
  const float* ff2_w   = (const float*)d_in[24];
  const float* ff2_b   = (const float*)d_in[25];
  const float* ln_g    = (const float*)d_in[26];
  const float* ln_b    = (const float*)d_in[27];

  float* out = (float*)d_out;
  float* dec_out = out;            // (8,48,64)
  float* sel = out + 8*48*64;      // (8,48,512)

  char* base = (char*)d_ws;
  size_t cur = 0;
  auto alloc = [&](size_t bytes)->char*{
    char* pt = base + cur;
    cur += (bytes + 255) & ~(size_t)255;
    return pt;
  };
  // --- contiguous zero-init region: flags | z accum | emb slots ---
  unsigned* fl  = (unsigned*)alloc((size_t)8*48*9*16*4);          // 221184 B
  float* zacc   = (float*)alloc((size_t)8*48*8*512*4);            // 6.29 MB
  float* emb    = (float*)alloc((size_t)49*8*512*4);              // 0.80 MB
  size_t zero_span = cur;                                          // from fl
  // --- rest of workspace ---
  float* Vpriv  = (float*)alloc((size_t)128*4*48*64*4);           // 6.3 MB
  ushort* WqkvH = (ushort*)alloc((size_t)4*1536*512*2);
  ushort* WoH   = (ushort*)alloc((size_t)4*512*512*2);
  ushort* Wf1H  = (ushort*)alloc((size_t)4*2048*512*2);
  ushort* Wf2H  = (ushort*)alloc((size_t)4*512*2048*2);
  float* Wt_mm    = (float*)alloc((size_t)64*512*4);
  float* Wt_se    = (float*)alloc((size_t)1024*512*4);
  float* Wt_ca_in = (float*)alloc((size_t)512*1536*4);
  float* Wt_ca_out= (float*)alloc((size_t)512*512*4);
  float* Wt_xa_v  = (float*)alloc((size_t)4*512*512*4);
  float* Wt_xa_o  = (float*)alloc((size_t)4*512*512*4);
  float* xa_c  = (float*)alloc((size_t)4*384*512*4);
  float* pe    = (float*)alloc((size_t)48*512*4);
  float* qh    = (float*)alloc((size_t)384*512*4);
  float* khb   = (float*)alloc((size_t)512*512*4);
  float* vhb   = (float*)alloc((size_t)512*512*4);
  float* attno = (float*)alloc((size_t)384*512*4);
  float* xtmp  = (float*)alloc((size_t)384*512*4);
  float* catb  = (float*)alloc((size_t)8*1024*4);
  float* embt  = (float*)alloc((size_t)8*512*4);

  hipMemsetAsync(fl, 0, zero_span, stream);

  dim3 tb(32,8);
  // f16 casts (original [out][in] layout, contiguous rows)
  k_casthf<<<(4*1536*512+255)/256, 256, 0, stream>>>(sa_in_w, (__half*)WqkvH, 4*1536*512);
  k_casthf<<<(4*512*512+255)/256, 256, 0, stream>>>(sa_out_w, (__half*)WoH,  4*512*512);
  k_casthf<<<(4*2048*512+255)/256, 256, 0, stream>>>(ff1_w,  (__half*)Wf1H, 4*2048*512);
  k_casthf<<<(4*512*2048+255)/256, 256, 0, stream>>>(ff2_w,  (__half*)Wf2H, 4*512*2048);
  // fp32 transposes for the precompute GEMMs
  for (int l=0; l<4; ++l){
    k_transpose<<<dim3(16,16), tb, 0, stream>>>(xa_in_w + (size_t)l*1536*512 + (size_t)1024*512, Wt_xa_v + (size_t)l*512*512, 512, 512);
    k_transpose<<<dim3(16,16), tb, 0, stream>>>(xa_out_w + (size_t)l*512*512, Wt_xa_o + (size_t)l*512*512, 512, 512);
  }
  k_transpose<<<dim3(16,48), tb, 0, stream>>>(ca_in_w,  Wt_ca_in, 1536, 512);
  k_transpose<<<dim3(16,16), tb, 0, stream>>>(ca_out_w, Wt_ca_out, 512, 512);
  k_transpose<<<dim3(32,16), tb, 0, stream>>>(se_w,  Wt_se, 512, 1024);
  k_transpose<<<dim3(2,16),  tb, 0, stream>>>(mm_w,  Wt_mm, 512, 64);

  k_pe<<<96, 256, 0, stream>>>(pe);

  // sel = MHA(content, style_hiddens, style_hiddens), nh=1
  k_linear<<<dim3(4,48), 256, 0, stream>>>(content, 512, Wt_ca_in,        1536, ca_in_b,        qh,  512, 512, 512);
  k_linear<<<dim3(4,64), 256, 0, stream>>>(shid,    512, Wt_ca_in + 512,  1536, ca_in_b + 512,  khb, 512, 512, 512);
  k_linear<<<dim3(4,64), 256, 0, stream>>>(shid,    512, Wt_ca_in + 1024, 1536, ca_in_b + 1024, vhb, 512, 512, 512);
  k_sel_attn<<<384, 256, 0, stream>>>(qh, khb, vhb, attno);
  k_linear<<<dim3(4,48), 256, 0, stream>>>(attno, 512, Wt_ca_out, 512, ca_out_b, sel, 512, 512, 512);

  // cross-attn constants (diagonal mask -> one-hot softmax)
  for (int l=0; l<4; ++l){
    k_linear<<<dim3(4,48), 256, 0, stream>>>(content, 512, Wt_xa_v + (size_t)l*512*512, 512,
                                             xa_in_b + l*1536 + 1024, xtmp, 512, 512, 512);
    k_linear<<<dim3(4,48), 256, 0, stream>>>(xtmp, 512, Wt_xa_o + (size_t)l*512*512, 512,
                                             xa_out_b + l*512, xa_c + (size_t)l*384*512, 512, 512, 512);
  }

  // emb slot 0
  k_linear<<<dim3(4,1), 256, 0, stream>>>(init_st, 64, Wt_mm, 512, mm_b, catb, 1024, 512, 64);
  k_cat_tail<<<16, 256, 0, stream>>>(sel, catb);
  k_linear<<<dim3(4,1), 256, 0, stream>>>(catb, 1024, Wt_se, 512, se_b, embt, 512, 512, 1024);
  k_add_style<<<16, 256, 0, stream>>>(embt, style, emb);

  DP p;
  p.fl = fl; p.z = zacc; p.emb = emb; p.Vpriv = Vpriv;
  p.Wqkv = WqkvH; p.Wo = WoH; p.Wf1 = Wf1H; p.Wf2 = Wf2H;
  p.xa_c = xa_c; p.pe = pe;
  p.sa_in_b = sa_in_b; p.sa_out_b = sa_out_b; p.ff1_b = ff1_b; p.ff2_b = ff2_b;
  p.mmr_w = mmr_w; p.mmr_b = mmr_b; p.mm_w = mm_w; p.mm_b = mm_b;
  p.se_w = se_w; p.se_b = se_b; p.ln_g = ln_g; p.ln_b = ln_b;
  p.style = style; p.sel = sel; p.dec_out = dec_out;

  k_decode<<<dim3(128), dim3(256), 0, stream>>>(p);
}

// Round 2
// 5263.758 us; speedup vs baseline: 1.2859x; 1.2112x over previous
//
#include <hip/hip_runtime.h>
#include <hip/hip_fp16.h>

// Problem constants: B=8, F=48, S=64, D=512, NH=8, L=4, DFF=2048, M=64, PERIOD=30

// ---------------- f16 dot2 helpers ----------------
typedef _Float16 h2 __attribute__((ext_vector_type(2)));
__device__ inline h2 u2h(unsigned u){ union{unsigned u; h2 h;} c; c.u=u; return c.h; }
#if __has_builtin(__builtin_amdgcn_fdot2)
__device__ inline float FDOT2(h2 a, h2 b, float c){ return __builtin_amdgcn_fdot2(a, b, c, false); }
#else
__device__ inline float FDOT2(h2 a, h2 b, float c){
  return fmaf((float)a.y, (float)b.y, fmaf((float)a.x, (float)b.x, c));
}
#endif

__device__ inline float aload(const float* p){
  return __hip_atomic_load(p, __ATOMIC_RELAXED, __HIP_MEMORY_SCOPE_AGENT);
}
__device__ inline void astore(float* p, float v){
  __hip_atomic_store(p, v, __ATOMIC_RELAXED, __HIP_MEMORY_SCOPE_AGENT);
}
__device__ inline float2 aload2(const float* base, int pairIdx){
  union { unsigned long long u; float2 f; } c;
  c.u = __hip_atomic_load((const unsigned long long*)base + pairIdx,
                          __ATOMIC_RELAXED, __HIP_MEMORY_SCOPE_AGENT);
  return c.f;
}

// dot of n (multiple of 8) f16 weights (contiguous row) with f16 x (LDS),
// fp32 accumulation via v_dot2_f32_f16, 4 independent chains for ILP.
__device__ inline float dot_f16(const ushort* wrow, const ushort* xh, int n){
  const uint4* w4 = (const uint4*)wrow;
  const uint4* x4 = (const uint4*)xh;
  float a0=0.f, a1=0.f, a2=0.f, a3=0.f;
  #pragma unroll 4
  for (int i=0; i<(n>>3); ++i){
    uint4 w = w4[i], x = x4[i];
    a0 = FDOT2(u2h(w.x), u2h(x.x), a0);
    a1 = FDOT2(u2h(w.y), u2h(x.y), a1);
    a2 = FDOT2(u2h(w.z), u2h(x.z), a2);
    a3 = FDOT2(u2h(w.w), u2h(x.w), a3);
  }
  return (a0+a1)+(a2+a3);
}
// dot of n (multiple of 4) fp32 weights with fp32 x, 4 accumulators
__device__ inline float dot_f32(const float* wrow, const float* x, int n){
  const float4* w4 = (const float4*)wrow;
  float a0=0.f, a1=0.f, a2=0.f, a3=0.f;
  #pragma unroll 4
  for (int i=0; i<(n>>2); ++i){
    float4 w = w4[i];
    const float* xp = x + i*4;
    a0 = fmaf(w.x, xp[0], a0); a1 = fmaf(w.y, xp[1], a1);
    a2 = fmaf(w.z, xp[2], a2); a3 = fmaf(w.w, xp[3], a3);
  }
  return (a0+a1)+(a2+a3);
}

// ---------------- transpose (src R x C -> dst C x R) ----------------
__global__ void k_transpose(const float* __restrict__ src, float* __restrict__ dst, int R, int C){
  __shared__ float tile[32][33];
  int cb = blockIdx.x*32, rb = blockIdx.y*32;
  int tx = threadIdx.x, ty = threadIdx.y;   // blockDim (32,8)
  for (int i=ty; i<32; i+=8) tile[i][tx] = src[(size_t)(rb+i)*C + cb+tx];
  __syncthreads();
  for (int i=ty; i<32; i+=8) dst[(size_t)(cb+i)*R + rb+tx] = tile[tx][i];
}

// cast fp32 -> f16 (same layout)
__global__ void k_casthf(const float* __restrict__ s, __half* __restrict__ d, int n){
  int i = blockIdx.x*256 + threadIdx.x;
  if (i < n) d[i] = __float2half(s[i]);
}

// ---------------- generic linear with optional z-batching ----------------
// C[z][r,o] = sum_d A[z][r,d]*Wt[z][d,o] + bias[z][o]
__global__ void k_linear(const float* __restrict__ A, int lda,
                         const float* __restrict__ Wt, int ldw,
                         const float* __restrict__ bias,
                         float* __restrict__ C, int ldc,
                         int O, int Din,
                         size_t aStr, size_t wStr, size_t bStr, size_t cStr){
  __shared__ float xs[8*1024];
  __shared__ float red[4096];
  int tid = threadIdx.x;
  int r0 = blockIdx.y*8;
  int z = blockIdx.z;
  const float* Az = A + (size_t)z*aStr;
  const float* Wz = Wt + (size_t)z*wStr;
  const float* Bz = bias ? bias + (size_t)z*bStr : nullptr;
  float* Cz = C + (size_t)z*cStr;
  for (int idx=tid; idx<8*Din; idx+=256){
    int ri = idx / Din, d = idx - ri*Din;
    xs[idx] = Az[(size_t)(r0+ri)*lda + d];
  }
  __syncthreads();
  int op = tid & 63, kp = tid >> 6;
  int o = blockIdx.x*128 + op*2;
  int dq = Din >> 2;
  float a0[8] = {0,0,0,0,0,0,0,0}, a1[8] = {0,0,0,0,0,0,0,0};
  for (int d = kp*dq; d < kp*dq+dq; ++d){
    float2 w = *reinterpret_cast<const float2*>(&Wz[(size_t)d*ldw + o]);
    #pragma unroll
    for (int ri=0; ri<8; ++ri){ float x = xs[ri*Din+d]; a0[ri] += x*w.x; a1[ri] += x*w.y; }
  }
  #pragma unroll
  for (int ri=0; ri<8; ++ri){
    red[((kp*64+op)*8+ri)*2]   = a0[ri];
    red[((kp*64+op)*8+ri)*2+1] = a1[ri];
  }
  __syncthreads();
  for (int idx = tid; idx < 1024; idx += 256){
    int ri = idx >> 7, oc = idx & 127;
    int opp = oc >> 1, c = oc & 1;
    float v = red[((0*64+opp)*8+ri)*2 + c] + red[((1*64+opp)*8+ri)*2 + c]
            + red[((2*64+opp)*8+ri)*2 + c] + red[((3*64+opp)*8+ri)*2 + c];
    int oo = blockIdx.x*128 + oc;
    if (Bz) v += Bz[oo];
    Cz[(size_t)(r0+ri)*ldc + oo] = v;
  }
}

// ---------------- PE table ----------------
__global__ void k_pe(float* __restrict__ pe){
  int idx = blockIdx.x*256 + threadIdx.x;  // 48*512
  int t = idx >> 9, d = idx & 511;
  int p = t % 30;
  int i2 = d & ~1;
  float div = __expf(-(float)i2 * (9.210340371976184f/512.f));
  float ang = (float)p * div;
  pe[idx] = (d & 1) ? cosf(ang) : sinf(ang);
}

// ---------------- sel attention (nh=1) ----------------
__global__ void k_sel_attn(const float* __restrict__ qh, const float* __restrict__ kh,
                           const float* __restrict__ vh, float* __restrict__ o){
  int bf = blockIdx.x;           // b*48+f
  int b  = bf / 48;
  int tid = threadIdx.x;
  __shared__ float qs[512];
  __shared__ float ps[64];
  qs[tid] = qh[(size_t)bf*512 + tid];
  qs[tid+256] = qh[(size_t)bf*512 + tid + 256];
  __syncthreads();
  if (tid < 64){
    const float* kr = kh + (size_t)(b*64+tid)*512;
    float a = 0.f;
    for (int d=0; d<512; ++d) a += qs[d]*kr[d];
    ps[tid] = a * 0.04419417382415922f;
  }
  __syncthreads();
  if (tid == 0){
    float m = -1e30f;
    for (int j=0;j<64;++j) m = fmaxf(m, ps[j]);
    float s = 0.f;
    for (int j=0;j<64;++j){ float e = __expf(ps[j]-m); ps[j]=e; s+=e; }
    float iv = 1.f/s;
    for (int j=0;j<64;++j) ps[j] *= iv;
  }
  __syncthreads();
  float a0=0.f, a1=0.f;
  for (int j=0;j<64;++j){
    const float* vr = vh + (size_t)(b*64+j)*512;
    float pj = ps[j];
    a0 += pj*vr[tid]; a1 += pj*vr[tid+256];
  }
  o[(size_t)bf*512+tid] = a0;
  o[(size_t)bf*512+tid+256] = a1;
}

// ---------------- tiny glue ----------------
__global__ void k_cat_tail(const float* __restrict__ sel, float* __restrict__ cat){
  int idx = blockIdx.x*256 + threadIdx.x;  // 8*512
  int b = idx >> 9, d = idx & 511;
  cat[b*1024 + 512 + d] = sel[(size_t)(b*48)*512 + d];
}
// write emb slot 0 in pair-slot layout: element e -> dword ((e&255)<<1)|(e>>8)
__global__ void k_add_style(const float* __restrict__ embt, const float* __restrict__ style,
                            float* __restrict__ emb){
  int idx = blockIdx.x*256 + threadIdx.x;  // 8*512
  int b = idx >> 9, e = idx & 511;
  int slot = ((e & 255) << 1) | (e >> 8);
  emb[b*512 + slot] = embt[idx] + style[idx];
}

// ---------------- persistent decode kernel ----------------
// 128 blocks (<=256 CUs -> all co-resident), one batch per 16 WGs.
// role = (i&7)*2 + ((i>>3)&1): blocks sharing an XCD (i%8) share 2 roles,
// keeping the per-XCD weight working set ~3.4 MB (< 4 MB L2).
// Cross-WG sync: per-stage relaxed agent counters (no release fences —
// agent-scope atomics are coherent at the memory-side point; the pre-barrier
// vmcnt(0) drain orders the z adds before the counter increment).
// z / emb use pair-slot layout: element e lives at dword ((e&255)<<1)|(e>>8)
// so each thread reads its two elements (e, e+256) with ONE 8-byte atomic load.
struct DP {
  unsigned* fl;        // counters: [b][t][stage 0..8] at stride 16 dwords
  float* z;            // [b][t][8 slots][512] accumulators, pair-slot layout (memset 0)
  float* emb;          // [t 0..48][b][512] pair-slot layout (memset 0; slot0 from precompute)
  const ushort *Wqkv, *Wo, *Wf1, *Wf2;   // f16, original [out][in] layout
  const float *xa_c, *pe;
  const float *sa_in_b, *sa_out_b, *ff1_b, *ff2_b;
  const float *mmr_w, *mmr_b, *mm_w, *mm_b, *se_w, *se_b;
  const float *ln_g, *ln_b, *style, *sel;
  float* dec_out;
};

__launch_bounds__(256, 1)
__global__ void k_decode(DP p){
  const int tid = threadIdx.x;
  const int i = blockIdx.x;
  const int role = ((i & 7) << 1) | ((i >> 3) & 1);
  const int b = i >> 4;
  const int h = role >> 1, half = role & 1;
  const float slope = exp2f(-(float)(h+1));

  __shared__ float kc[4*48*65];   // K cache, fp32, pad 65 vs bank conflicts (49.9 KB)
  __shared__ float vs[4*48*64];   // V cache in LDS (49.2 KB) — was global
  __shared__ float xs[512];       // fp32 x (tail only)
  __shared__ float red[512];
  __shared__ float qs[64], ps[64], d64[64];
  __shared__ float ns[512];
  __shared__ float lnred[8];
  __shared__ __align__(16) __half xhh[512];   // f16 x for dot2 paths
  __shared__ __align__(16) __half anh[64];    // f16 attn-out (head)
  __shared__ __align__(16) __half hsh[128];   // f16 FF hidden slice

  unsigned* flb = p.fl + (size_t)b*48*9*16;
  float* zb = p.z + (size_t)b*48*8*512;

  auto waitc = [&](int t, int s){
    const unsigned* c = flb + (size_t)(t*9+s)*16;
    while (__hip_atomic_load(c, __ATOMIC_RELAXED, __HIP_MEMORY_SCOPE_AGENT) < 16u)
      __builtin_amdgcn_s_sleep(1);
  };
  auto post = [&](int t, int s){
    __syncthreads();   // all waves drain vmcnt (atomics acked) at barrier
    if (tid == 0)
      __hip_atomic_fetch_add(flb + (size_t)(t*9+s)*16, 1u,
                             __ATOMIC_RELAXED, __HIP_MEMORY_SCOPE_AGENT);
  };
  // LN over 512 (2 elems/thread). Results returned in r0/r1 (this thread's
  // elems tid and tid+256); optionally stored to fp32 out and/or f16 oh.
  auto lnorm = [&](float v0, float v1, const float* g, const float* bb,
                   float* out, __half* oh, float& r0, float& r1){
    float s = v0 + v1, q = v0*v0 + v1*v1;
    #pragma unroll
    for (int off=32; off>0; off>>=1){ s += __shfl_xor(s, off, 64); q += __shfl_xor(q, off, 64); }
    if ((tid & 63) == 0){ lnred[tid>>6] = s; lnred[4+(tid>>6)] = q; }
    __syncthreads();
    s = lnred[0]+lnred[1]+lnred[2]+lnred[3];
    q = lnred[4]+lnred[5]+lnred[6]+lnred[7];
    float mu = s * (1.f/512.f);
    float rs = rsqrtf(q*(1.f/512.f) - mu*mu + 1e-5f);
    r0 = (v0-mu)*rs*g[tid]     + bb[tid];
    r1 = (v1-mu)*rs*g[tid+256] + bb[tid+256];
    if (out){ out[tid] = r0; out[tid+256] = r1; }
    if (oh){ oh[tid] = __float2half(r0); oh[tid+256] = __float2half(r1); }
    __syncthreads();
  };

  for (int t=0; t<48; ++t){
    for (int l=0; l<4; ++l){
      // prefetch cross-attn constant for stage B (cold HBM) before any waiting
      const float* xac = p.xa_c + ((size_t)l*384 + b*48 + t)*512;
      float xa0 = xac[tid], xa1 = xac[tid+256];

      // ===== stage A: x prep + QKV (own head) + attention + O-partial =====
      float x0, x1;                // this thread's x (residual source)
      if (l == 0){
        float pe0 = p.pe[t*512+tid], pe1 = p.pe[t*512+tid+256]; // prefetch
        if (t > 0) waitc(t-1, 8);
        float2 e = aload2(p.emb + ((size_t)t*8+b)*512, tid);
        x0 = e.x + pe0; x1 = e.y + pe1;
        xhh[tid]     = __float2half(x0);
        xhh[tid+256] = __float2half(x1);
        __syncthreads();
      } else {
        waitc(t, (l-1)*2+1);
        float2 z = aload2(zb + ((size_t)t*8 + (l-1)*2+1)*512, tid);
        lnorm(z.x, z.y, p.ln_g + ((l-1)*3+2)*512, p.ln_b + ((l-1)*3+2)*512,
              nullptr, xhh, x0, x1);
      }
      // QKV for head h: threads 0..63 q, 64..127 k, 128..191 v
      if (tid < 192){
        int sec = tid >> 6, dch = tid & 63;
        int row = sec*512 + h*64 + dch;
        float acc = dot_f16(p.Wqkv + ((size_t)l*1536+row)*512, (const ushort*)xhh, 512)
                  + p.sa_in_b[l*1536+row];
        if (sec == 0) qs[dch] = acc;
        else if (sec == 1) kc[(l*48+t)*65 + dch] = acc;
        else vs[(l*48+t)*64 + dch] = acc;
      }
      __syncthreads();
      // scores + softmax (wave 0)
      if (tid < 64){
        float sc = -1e30f;
        if (tid <= t){
          float a = 0.f;
          const float* kr = &kc[(l*48+tid)*65];
          #pragma unroll
          for (int d=0; d<64; ++d) a = fmaf(qs[d], kr[d], a);
          sc = a*0.125f - ((t-tid) >= 30 ? slope : 0.f);
        }
        float m = sc;
        #pragma unroll
        for (int off=32; off>0; off>>=1) m = fmaxf(m, __shfl_xor(m, off, 64));
        float e = (tid <= t) ? __expf(sc-m) : 0.f;
        float s = e;
        #pragma unroll
        for (int off=32; off>0; off>>=1) s += __shfl_xor(s, off, 64);
        ps[tid] = e / s;
      }
      __syncthreads();
      // PV: d = tid&63, j-quarter = tid>>6
      {
        int d = tid & 63, jq = tid >> 6;
        float a = 0.f;
        for (int j=jq*12; j<jq*12+12; ++j)
          if (j <= t) a = fmaf(ps[j], vs[(l*48+j)*64 + d], a);
        red[tid] = a;
      }
      __syncthreads();
      if (tid < 64) anh[tid] = __float2half(red[tid]+red[64+tid]+red[128+tid]+red[192+tid]);
      __syncthreads();
      // O-partial over this head's 64 dims, out-half per `half`
      {
        int o = half*256 + tid;
        float acc = dot_f16(p.Wo + (((size_t)l*512+o)*512 + h*64), (const ushort*)anh, 64);
        if (h == 0) acc += (half ? x1 : x0) + p.sa_out_b[l*512+o];  // residual+bias once
        unsafeAtomicAdd(zb + ((size_t)t*8 + l*2)*512 + ((tid<<1)|half), acc);
      }
      post(t, l*2);

      // ===== stage B: LN + cross-const + LN + FF1 slice + FF2 partial =====
      waitc(t, l*2);
      float r0, r1;   // u2 (this thread's elems) for FF2 residual
      {
        float2 z = aload2(zb + ((size_t)t*8 + l*2)*512, tid);
        float w0, w1;
        lnorm(z.x, z.y, p.ln_g + (l*3)*512, p.ln_b + (l*3)*512, nullptr, nullptr, w0, w1);
        float u0 = w0 + xa0, u1 = w1 + xa1;
        lnorm(u0, u1, p.ln_g + (l*3+1)*512, p.ln_b + (l*3+1)*512, nullptr, xhh, r0, r1);
      }
      {
        int oo = tid & 127, hh = tid >> 7;
        int row = role*128 + oo;
        red[tid] = dot_f16(p.Wf1 + ((size_t)l*2048+row)*512 + hh*256,
                           (const ushort*)xhh + hh*256, 256);
      }
      __syncthreads();
      if (tid < 128){
        float v = red[tid] + red[128+tid] + p.ff1_b[l*2048 + role*128 + tid];
        hsh[tid] = __float2half(fmaxf(v, 0.f));
      }
      __syncthreads();
      {
        float a0 = dot_f16(p.Wf2 + ((size_t)l*512+tid)*2048 + role*128, (const ushort*)hsh, 128);
        float a1 = dot_f16(p.Wf2 + ((size_t)l*512+tid+256)*2048 + role*128, (const ushort*)hsh, 128);
        if (role == 0){
          a0 += r0 + p.ff2_b[l*512+tid];
          a1 += r1 + p.ff2_b[l*512+tid+256];
        }
        float* zs = zb + ((size_t)t*8 + l*2+1)*512;
        unsafeAtomicAdd(zs + (tid<<1),     a0);
        unsafeAtomicAdd(zs + (tid<<1) + 1, a1);
      }
      post(t, l*2+1);
    } // layers

    // ===== tail: LN + mmr -> dec_out, mm -> new, se -> next emb =====
    waitc(t, 7);
    {
      float2 z = aload2(zb + ((size_t)t*8 + 7)*512, tid);
      float w0, w1;
      lnorm(z.x, z.y, p.ln_g + 11*512, p.ln_b + 11*512, xs, nullptr, w0, w1);
    }
    {
      int o = tid & 63, kq = tid >> 6;
      red[tid] = dot_f32(p.mmr_w + (size_t)o*512 + kq*128, xs + kq*128, 128);
    }
    __syncthreads();
    if (tid < 64){
      float v = red[tid]+red[64+tid]+red[128+tid]+red[192+tid] + p.mmr_b[tid];
      d64[tid] = v;
      if (role == 0) p.dec_out[((size_t)b*48+t)*64 + tid] = v;
    }
    __syncthreads();
    {
      ns[tid]     = dot_f32(p.mm_w + (size_t)tid*64,       d64, 64) + p.mm_b[tid];
      ns[tid+256] = dot_f32(p.mm_w + (size_t)(tid+256)*64, d64, 64) + p.mm_b[tid+256];
    }
    __syncthreads();
    {
      int oo = tid & 31, part = tid >> 5;   // 8 parts x 128
      int o = role*32 + oo;
      float acc;
      if (part < 4)
        acc = dot_f32(p.se_w + (size_t)o*1024 + part*128, ns + part*128, 128);
      else
        acc = dot_f32(p.se_w + (size_t)o*1024 + part*128,
                      p.sel + ((size_t)b*48+t)*512 + (part-4)*128, 128);
      red[tid] = acc;
    }
    __syncthreads();
    if (tid < 32){
      float v = 0.f;
      #pragma unroll
      for (int k8=0; k8<8; ++k8) v += red[k8*32+tid];
      int o = role*32 + tid;
      v += p.se_b[o] + p.style[(size_t)b*512+o];
      int slot = ((o & 255) << 1) | (o >> 8);
      astore(p.emb + ((size_t)(t+1)*8+b)*512 + slot, v);
    }
    post(t, 8);
  } // t
}

// ---------------- host ----------------
extern "C" void kernel_launch(void* const* d_in, const int* in_sizes, int n_in,
                              void* d_out, int out_size, void* d_ws, size_t ws_size,
                              hipStream_t stream){
  (void)in_sizes; (void)n_in; (void)out_size; (void)ws_size;
  const float* content = (const float*)d_in[0];
  const float* style   = (const float*)d_in[1];
  const float* shid    = (const float*)d_in[2];
  const float* init_st = (const float*)d_in[3];
  const float* ca_in_w = (const float*)d_in[4];
  const float* ca_in_b = (const float*)d_in[5];
  const float* ca_out_w= (const float*)d_in[6];
  const float* ca_out_b= (const float*)d_in[7];
  const float* se_w    = (const float*)d_in[8];
  const float* se_b    = (const float*)d_in[9];
  const float* mm_w    = (const float*)d_in[10];
  const float* mm_b    = (const float*)d_in[11];
  const float* mmr_w   = (const float*)d_in[12];
  const float* mmr_b   = (const float*)d_in[13];
  const float* sa_in_w = (const float*)d_in[14];
  const float* sa_in_b = (const float*)d_in[15];
  const float* sa_out_w= (const float*)d_in[16];
  const float* sa_out_b= (const float*)d_in[17];
  const float* xa_in_w = (const float*)d_in[18];
  const float* xa_in_b = (const float*)d_in[19];
  const float* xa_out_w= (const float*)d_in[20];
  const float* xa_out_b= (const float*)d_in[21];
  const float* ff1_w   = (const float*)d_in[22];
  const float* ff1_b   = (const float*)d_in[23];
  const float* ff2_w   = (const float*)d_in[24];
  const float* ff2_b   = (const float*)d_in[25];
  const float* ln_g    = (const float*)d_in[26];
  const float* ln_b    = (const float*)d_in[27];

  float* out = (float*)d_out;
  float* dec_out = out;            // (8,48,64)
  float* sel = out + 8*48*64;      // (8,48,512)

  char* base = (char*)d_ws;
  size_t cur = 0;
  auto alloc = [&](size_t bytes)->char*{
    char* pt = base + cur;
    cur += (bytes + 255) & ~(size_t)255;
    return pt;
  };
  // --- contiguous zero-init region: counters | z accum | emb slots ---
  unsigned* fl  = (unsigned*)alloc((size_t)8*48*9*16*4);          // 221184 B
  float* zacc   = (float*)alloc((size_t)8*48*8*512*4);            // 6.29 MB
  float* emb    = (float*)alloc((size_t)49*8*512*4);              // 0.80 MB
  size_t zero_span = cur;                                          // from fl
  // --- rest of workspace ---
  ushort* WqkvH = (ushort*)alloc((size_t)4*1536*512*2);
  ushort* WoH   = (ushort*)alloc((size_t)4*512*512*2);
  ushort* Wf1H  = (ushort*)alloc((size_t)4*2048*512*2);
  ushort* Wf2H  = (ushort*)alloc((size_t)4*512*2048*2);
  float* Wt_mm    = (float*)alloc((size_t)64*512*4);
  float* Wt_se    = (float*)alloc((size_t)1024*512*4);
  float* Wt_ca_in = (float*)alloc((size_t)512*1536*4);
  float* Wt_ca_out= (float*)alloc((size_t)512*512*4);
  float* Wt_xa_v  = (float*)alloc((size_t)4*512*512*4);
  float* Wt_xa_o  = (float*)alloc((size_t)4*512*512*4);
  float* xa_c  = (float*)alloc((size_t)4*384*512*4);
  float* pe    = (float*)alloc((size_t)48*512*4);
  float* qh    = (float*)alloc((size_t)384*512*4);
  float* khb   = (float*)alloc((size_t)512*512*4);   // K then V: must stay adjacent
  float* vhb   = (float*)alloc((size_t)512*512*4);
  float* attno = (float*)alloc((size_t)384*512*4);
  float* xtmp4 = (float*)alloc((size_t)4*384*512*4);
  float* catb  = (float*)alloc((size_t)8*1024*4);
  float* embt  = (float*)alloc((size_t)8*512*4);
  (void)vhb;

  hipMemsetAsync(fl, 0, zero_span, stream);

  dim3 tb(32,8);
  // f16 casts (original [out][in] layout, contiguous rows)
  k_casthf<<<(4*1536*512+255)/256, 256, 0, stream>>>(sa_in_w, (__half*)WqkvH, 4*1536*512);
  k_casthf<<<(4*512*512+255)/256, 256, 0, stream>>>(sa_out_w, (__half*)WoH,  4*512*512);
  k_casthf<<<(4*2048*512+255)/256, 256, 0, stream>>>(ff1_w,  (__half*)Wf1H, 4*2048*512);
  k_casthf<<<(4*512*2048+255)/256, 256, 0, stream>>>(ff2_w,  (__half*)Wf2H, 4*512*2048);
  // fp32 transposes for the precompute GEMMs
  for (int l=0; l<4; ++l){
    k_transpose<<<dim3(16,16), tb, 0, stream>>>(xa_in_w + (size_t)l*1536*512 + (size_t)1024*512, Wt_xa_v + (size_t)l*512*512, 512, 512);
    k_transpose<<<dim3(16,16), tb, 0, stream>>>(xa_out_w + (size_t)l*512*512, Wt_xa_o + (size_t)l*512*512, 512, 512);
  }
  k_transpose<<<dim3(16,48), tb, 0, stream>>>(ca_in_w,  Wt_ca_in, 1536, 512);
  k_transpose<<<dim3(16,16), tb, 0, stream>>>(ca_out_w, Wt_ca_out, 512, 512);
  k_transpose<<<dim3(32,16), tb, 0, stream>>>(se_w,  Wt_se, 512, 1024);
  k_transpose<<<dim3(2,16),  tb, 0, stream>>>(mm_w,  Wt_mm, 512, 64);

  k_pe<<<96, 256, 0, stream>>>(pe);

  // sel = MHA(content, style_hiddens, style_hiddens), nh=1
  k_linear<<<dim3(4,48), 256, 0, stream>>>(content, 512, Wt_ca_in, 1536, ca_in_b, qh, 512, 512, 512, 0,0,0,0);
  // K and V batched (z=0:K, z=1:V); khb/vhb adjacent, column offset 512 per z
  k_linear<<<dim3(4,64,2), 256, 0, stream>>>(shid, 512, Wt_ca_in + 512, 1536, ca_in_b + 512, khb, 512, 512, 512,
                                             0, 512, 512, (size_t)512*512);
  k_sel_attn<<<384, 256, 0, stream>>>(qh, khb, vhb, attno);
  k_linear<<<dim3(4,48), 256, 0, stream>>>(attno, 512, Wt_ca_out, 512, ca_out_b, sel, 512, 512, 512, 0,0,0,0);

  // cross-attn constants (diagonal mask -> one-hot softmax), z-batched over l
  k_linear<<<dim3(4,48,4), 256, 0, stream>>>(content, 512, Wt_xa_v, 512, xa_in_b + 1024, xtmp4, 512, 512, 512,
                                             0, (size_t)512*512, 1536, (size_t)384*512);
  k_linear<<<dim3(4,48,4), 256, 0, stream>>>(xtmp4, 512, Wt_xa_o, 512, xa_out_b, xa_c, 512, 512, 512,
                                             (size_t)384*512, (size_t)512*512, 512, (size_t)384*512);

  // emb slot 0
  k_linear<<<dim3(4,1), 256, 0, stream>>>(init_st, 64, Wt_mm, 512, mm_b, catb, 1024, 512, 64, 0,0,0,0);
  k_cat_tail<<<16, 256, 0, stream>>>(sel, catb);
  k_linear<<<dim3(4,1), 256, 0, stream>>>(catb, 1024, Wt_se, 512, se_b, embt, 512, 512, 1024, 0,0,0,0);
  k_add_style<<<16, 256, 0, stream>>>(embt, style, emb);

  DP p;
  p.fl = fl; p.z = zacc; p.emb = emb;
  p.Wqkv = WqkvH; p.Wo = WoH; p.Wf1 = Wf1H; p.Wf2 = Wf2H;
  p.xa_c = xa_c; p.pe = pe;
  p.sa_in_b = sa_in_b; p.sa_out_b = sa_out_b; p.ff1_b = ff1_b; p.ff2_b = ff2_b;
  p.mmr_w = mmr_w; p.mmr_b = mmr_b; p.mm_w = mm_w; p.mm_b = mm_b;
  p.se_w = se_w; p.se_b = se_b; p.ln_g = ln_g; p.ln_b = ln_b;
  p.style = style; p.sel = sel; p.dec_out = dec_out;

  k_decode<<<dim3(128), dim3(256), 0, stream>>>(p);
}

// Round 4
// 5122.054 us; speedup vs baseline: 1.3215x; 1.0277x over previous
//
#include <hip/hip_runtime.h>
#include <hip/hip_fp16.h>

// Problem constants: B=8, F=48, S=64, D=512, NH=8, L=4, DFF=2048, M=64, PERIOD=30

// ---------------- f16 dot2 helpers ----------------
typedef _Float16 h2 __attribute__((ext_vector_type(2)));
__device__ inline h2 u2h(unsigned u){ union{unsigned u; h2 h;} c; c.u=u; return c.h; }
#if __has_builtin(__builtin_amdgcn_fdot2)
__device__ inline float FDOT2(h2 a, h2 b, float c){ return __builtin_amdgcn_fdot2(a, b, c, false); }
#else
__device__ inline float FDOT2(h2 a, h2 b, float c){
  return fmaf((float)a.y, (float)b.y, fmaf((float)a.x, (float)b.x, c));
}
#endif

__device__ inline float aload(const float* p){
  return __hip_atomic_load(p, __ATOMIC_RELAXED, __HIP_MEMORY_SCOPE_AGENT);
}
__device__ inline void astore(float* p, float v){
  __hip_atomic_store(p, v, __ATOMIC_RELAXED, __HIP_MEMORY_SCOPE_AGENT);
}

// dot of n (multiple of 8) f16 weights (contiguous row) with f16 x (LDS),
// fp32 accumulation via v_dot2_f32_f16, 4 independent chains for ILP.
__device__ inline float dot_f16(const ushort* wrow, const ushort* xh, int n){
  const uint4* w4 = (const uint4*)wrow;
  const uint4* x4 = (const uint4*)xh;
  float a0=0.f, a1=0.f, a2=0.f, a3=0.f;
  #pragma unroll 4
  for (int i=0; i<(n>>3); ++i){
    uint4 w = w4[i], x = x4[i];
    a0 = FDOT2(u2h(w.x), u2h(x.x), a0);
    a1 = FDOT2(u2h(w.y), u2h(x.y), a1);
    a2 = FDOT2(u2h(w.z), u2h(x.z), a2);
    a3 = FDOT2(u2h(w.w), u2h(x.w), a3);
  }
  return (a0+a1)+(a2+a3);
}
// dot of n (multiple of 4) fp32 weights with fp32 x, 4 accumulators
__device__ inline float dot_f32(const float* wrow, const float* x, int n){
  const float4* w4 = (const float4*)wrow;
  float a0=0.f, a1=0.f, a2=0.f, a3=0.f;
  #pragma unroll 4
  for (int i=0; i<(n>>2); ++i){
    float4 w = w4[i];
    const float* xp = x + i*4;
    a0 = fmaf(w.x, xp[0], a0); a1 = fmaf(w.y, xp[1], a1);
    a2 = fmaf(w.z, xp[2], a2); a3 = fmaf(w.w, xp[3], a3);
  }
  return (a0+a1)+(a2+a3);
}

// ---------------- transpose (src R x C -> dst C x R) ----------------
__global__ void k_transpose(const float* __restrict__ src, float* __restrict__ dst, int R, int C){
  __shared__ float tile[32][33];
  int cb = blockIdx.x*32, rb = blockIdx.y*32;
  int tx = threadIdx.x, ty = threadIdx.y;   // blockDim (32,8)
  for (int i=ty; i<32; i+=8) tile[i][tx] = src[(size_t)(rb+i)*C + cb+tx];
  __syncthreads();
  for (int i=ty; i<32; i+=8) dst[(size_t)(cb+i)*R + rb+tx] = tile[tx][i];
}

// cast fp32 -> f16 (same layout)
__global__ void k_casthf(const float* __restrict__ s, __half* __restrict__ d, int n){
  int i = blockIdx.x*256 + threadIdx.x;
  if (i < n) d[i] = __float2half(s[i]);
}

// ---------------- generic linear with optional z-batching ----------------
// C[z][r,o] = sum_d A[z][r,d]*Wt[z][d,o] + bias[z][o]
__global__ void k_linear(const float* __restrict__ A, int lda,
                         const float* __restrict__ Wt, int ldw,
                         const float* __restrict__ bias,
                         float* __restrict__ C, int ldc,
                         int O, int Din,
                         size_t aStr, size_t wStr, size_t bStr, size_t cStr){
  __shared__ float xs[8*1024];
  __shared__ float red[4096];
  int tid = threadIdx.x;
  int r0 = blockIdx.y*8;
  int z = blockIdx.z;
  const float* Az = A + (size_t)z*aStr;
  const float* Wz = Wt + (size_t)z*wStr;
  const float* Bz = bias ? bias + (size_t)z*bStr : nullptr;
  float* Cz = C + (size_t)z*cStr;
  for (int idx=tid; idx<8*Din; idx+=256){
    int ri = idx / Din, d = idx - ri*Din;
    xs[idx] = Az[(size_t)(r0+ri)*lda + d];
  }
  __syncthreads();
  int op = tid & 63, kp = tid >> 6;
  int o = blockIdx.x*128 + op*2;
  int dq = Din >> 2;
  float a0[8] = {0,0,0,0,0,0,0,0}, a1[8] = {0,0,0,0,0,0,0,0};
  for (int d = kp*dq; d < kp*dq+dq; ++d){
    float2 w = *reinterpret_cast<const float2*>(&Wz[(size_t)d*ldw + o]);
    #pragma unroll
    for (int ri=0; ri<8; ++ri){ float x = xs[ri*Din+d]; a0[ri] += x*w.x; a1[ri] += x*w.y; }
  }
  #pragma unroll
  for (int ri=0; ri<8; ++ri){
    red[((kp*64+op)*8+ri)*2]   = a0[ri];
    red[((kp*64+op)*8+ri)*2+1] = a1[ri];
  }
  __syncthreads();
  for (int idx = tid; idx < 1024; idx += 256){
    int ri = idx >> 7, oc = idx & 127;
    int opp = oc >> 1, c = oc & 1;
    float v = red[((0*64+opp)*8+ri)*2 + c] + red[((1*64+opp)*8+ri)*2 + c]
            + red[((2*64+opp)*8+ri)*2 + c] + red[((3*64+opp)*8+ri)*2 + c];
    int oo = blockIdx.x*128 + oc;
    if (Bz) v += Bz[oo];
    Cz[(size_t)(r0+ri)*ldc + oo] = v;
  }
}

// ---------------- PE table ----------------
__global__ void k_pe(float* __restrict__ pe){
  int idx = blockIdx.x*256 + threadIdx.x;  // 48*512
  int t = idx >> 9, d = idx & 511;
  int p = t % 30;
  int i2 = d & ~1;
  float div = __expf(-(float)i2 * (9.210340371976184f/512.f));
  float ang = (float)p * div;
  pe[idx] = (d & 1) ? cosf(ang) : sinf(ang);
}

// ---------------- sel attention (nh=1) ----------------
__global__ void k_sel_attn(const float* __restrict__ qh, const float* __restrict__ kh,
                           const float* __restrict__ vh, float* __restrict__ o){
  int bf = blockIdx.x;           // b*48+f
  int b  = bf / 48;
  int tid = threadIdx.x;
  __shared__ float qs[512];
  __shared__ float ps[64];
  qs[tid] = qh[(size_t)bf*512 + tid];
  qs[tid+256] = qh[(size_t)bf*512 + tid + 256];
  __syncthreads();
  if (tid < 64){
    const float* kr = kh + (size_t)(b*64+tid)*512;
    float a = 0.f;
    for (int d=0; d<512; ++d) a += qs[d]*kr[d];
    ps[tid] = a * 0.04419417382415922f;
  }
  __syncthreads();
  if (tid == 0){
    float m = -1e30f;
    for (int j=0;j<64;++j) m = fmaxf(m, ps[j]);
    float s = 0.f;
    for (int j=0;j<64;++j){ float e = __expf(ps[j]-m); ps[j]=e; s+=e; }
    float iv = 1.f/s;
    for (int j=0;j<64;++j) ps[j] *= iv;
  }
  __syncthreads();
  float a0=0.f, a1=0.f;
  for (int j=0;j<64;++j){
    const float* vr = vh + (size_t)(b*64+j)*512;
    float pj = ps[j];
    a0 += pj*vr[tid]; a1 += pj*vr[tid+256];
  }
  o[(size_t)bf*512+tid] = a0;
  o[(size_t)bf*512+tid+256] = a1;
}

// ---------------- tiny glue ----------------
__global__ void k_cat_tail(const float* __restrict__ sel, float* __restrict__ cat){
  int idx = blockIdx.x*256 + threadIdx.x;  // 8*512
  int b = idx >> 9, d = idx & 511;
  cat[b*1024 + 512 + d] = sel[(size_t)(b*48)*512 + d];
}
__global__ void k_add_style(const float* __restrict__ embt, const float* __restrict__ style,
                            float* __restrict__ emb){
  int idx = blockIdx.x*256 + threadIdx.x;  // 8*512 -> emb slot t=0
  emb[idx] = embt[idx] + style[idx];
}

// ---------------- persistent decode kernel ----------------
// 128 blocks x 512 threads (8 waves, 2/SIMD; LDS 107KB -> 1 WG/CU, all
// co-resident). One batch per 16 WGs. role = (i&7)*2 + ((i>>3)&1): blocks
// sharing an XCD (i%8) share 2 roles -> per-XCD weight set ~3.4MB (L2-res).
// Cross-WG sync: per-stage relaxed agent counters. IMPORTANT: the data load
// must be ISSUED only after the counter is observed ==16 (poll-then-load).
// A speculative load issued alongside the counter check can be serviced at
// the LLC before a producer's final add even when the counter check passes
// (independent requests, unordered service) -> stale data (R3 failure).
struct DP {
  unsigned* fl;        // counters: [b][t][stage 0..8] at stride 16 dwords
  float* z;            // [b][t][8 slots][512] accumulators (memset 0)
  float* emb;          // [t 0..48][b][512] (memset 0; slot0 from precompute)
  const ushort *Wqkv, *Wo, *Wf1, *Wf2;   // f16, original [out][in] layout
  const float *xa_c, *pe;
  const float *sa_in_b, *sa_out_b, *ff1_b, *ff2_b;
  const float *mmr_w, *mmr_b, *mm_w, *mm_b, *se_w, *se_b;
  const float *ln_g, *ln_b, *style, *sel;
  float* dec_out;
};

__launch_bounds__(512, 2)
__global__ void k_decode(DP p){
  const int tid = threadIdx.x;
  const int i = blockIdx.x;
  const int role = ((i & 7) << 1) | ((i >> 3) & 1);
  const int b = i >> 4;
  const int h = role >> 1, half = role & 1;
  const float slope = exp2f(-(float)(h+1));

  __shared__ float kc[4*48*65];   // K cache fp32, pad 65 (49.9 KB)
  __shared__ float vs[4*48*64];   // V cache fp32 (49.2 KB)
  __shared__ float xs[512];       // fp32 x (stage-A residual + tail)
  __shared__ float red[512];
  __shared__ float qs[64], ps[64], d64[64];
  __shared__ float ns[512];
  __shared__ float lnred[16];
  __shared__ __align__(16) __half xhh[512];   // f16 x for dot2 paths
  __shared__ __align__(16) __half anh[64];    // f16 attn-out (head)
  __shared__ __align__(16) __half hsh[128];   // f16 FF hidden slice

  unsigned* flb = p.fl + (size_t)b*48*9*16;
  float* zb = p.z + (size_t)b*48*8*512;

  // Poll the stage counter to 16, THEN load this thread's element (the load
  // must be issued after completion is observed — see header comment).
  auto waitz = [&](int t, int s, const float* src)->float{
    const unsigned* c = flb + (size_t)(t*9+s)*16;
    while (__hip_atomic_load(c, __ATOMIC_RELAXED, __HIP_MEMORY_SCOPE_AGENT) < 16u)
      __builtin_amdgcn_s_sleep(1);
    return aload(src + tid);
  };
  auto post = [&](int t, int s){
    __syncthreads();   // all waves drain vmcnt (atomics acked) at barrier
    if (tid == 0)
      __hip_atomic_fetch_add(flb + (size_t)(t*9+s)*16, 1u,
                             __ATOMIC_RELAXED, __HIP_MEMORY_SCOPE_AGENT);
  };
  // LN over 512, 1 elem/thread. Returns this thread's normalized element;
  // optionally stores to fp32 out / f16 oh.
  auto lnorm = [&](float v, const float* g, const float* bb,
                   float* out, __half* oh)->float{
    float s = v, q = v*v;
    #pragma unroll
    for (int off=32; off>0; off>>=1){ s += __shfl_xor(s, off, 64); q += __shfl_xor(q, off, 64); }
    if ((tid & 63) == 0){ lnred[tid>>6] = s; lnred[8+(tid>>6)] = q; }
    __syncthreads();
    s = 0.f; q = 0.f;
    #pragma unroll
    for (int w=0; w<8; ++w){ s += lnred[w]; q += lnred[8+w]; }
    float mu = s * (1.f/512.f);
    float rs = rsqrtf(q*(1.f/512.f) - mu*mu + 1e-5f);
    float r = (v-mu)*rs*g[tid] + bb[tid];
    if (out) out[tid] = r;
    if (oh) oh[tid] = __float2half(r);
    __syncthreads();
    return r;
  };

  for (int t=0; t<48; ++t){
    for (int l=0; l<4; ++l){
      // prefetch cross-attn constant for stage B (cold HBM) before any waiting
      const float* xac = p.xa_c + ((size_t)l*384 + b*48 + t)*512;
      float xa = xac[tid];

      // ===== stage A: x prep + QKV (own head) + attention + O-partial =====
      if (l == 0){
        float pe0 = p.pe[t*512+tid];             // prefetch
        float e;
        if (t > 0) e = waitz(t-1, 8, p.emb + ((size_t)t*8+b)*512);
        else       e = aload(p.emb + ((size_t)t*8+b)*512 + tid);
        float x = e + pe0;
        xs[tid] = x; xhh[tid] = __float2half(x);
        __syncthreads();
      } else {
        float z = waitz(t, (l-1)*2+1, zb + ((size_t)t*8 + (l-1)*2+1)*512);
        lnorm(z, p.ln_g + ((l-1)*3+2)*512, p.ln_b + ((l-1)*3+2)*512, xs, xhh);
      }
      // QKV for head h: 192 rows x 2-lane split (256-dots)
      if (tid < 384){
        int row = tid >> 1, piece = tid & 1;
        int sec = row >> 6, dch = row & 63;
        int wrow = sec*512 + h*64 + dch;
        float acc = dot_f16(p.Wqkv + ((size_t)l*1536+wrow)*512 + piece*256,
                            (const ushort*)xhh + piece*256, 256);
        acc += __shfl_xor(acc, 1, 64);
        if (piece == 0){
          acc += p.sa_in_b[l*1536+wrow];
          if (sec == 0) qs[dch] = acc;
          else if (sec == 1) kc[(l*48+t)*65 + dch] = acc;
          else vs[(l*48+t)*64 + dch] = acc;
        }
      }
      __syncthreads();
      // scores + softmax (wave 0)
      if (tid < 64){
        float sc = -1e30f;
        if (tid <= t){
          float a = 0.f;
          const float* kr = &kc[(l*48+tid)*65];
          #pragma unroll
          for (int d=0; d<64; ++d) a = fmaf(qs[d], kr[d], a);
          sc = a*0.125f - ((t-tid) >= 30 ? slope : 0.f);
        }
        float m = sc;
        #pragma unroll
        for (int off=32; off>0; off>>=1) m = fmaxf(m, __shfl_xor(m, off, 64));
        float e = (tid <= t) ? __expf(sc-m) : 0.f;
        float s = e;
        #pragma unroll
        for (int off=32; off>0; off>>=1) s += __shfl_xor(s, off, 64);
        ps[tid] = e / s;
      }
      __syncthreads();
      // PV: d = tid&63, j-eighth = tid>>6 (6 js each)
      {
        int d = tid & 63, jq = tid >> 6;
        float a = 0.f;
        for (int j=jq*6; j<jq*6+6; ++j)
          if (j <= t) a = fmaf(ps[j], vs[(l*48+j)*64 + d], a);
        red[tid] = a;
      }
      __syncthreads();
      if (tid < 64){
        float a = red[tid]+red[64+tid]+red[128+tid]+red[192+tid]
                + red[256+tid]+red[320+tid]+red[384+tid]+red[448+tid];
        anh[tid] = __float2half(a);
      }
      __syncthreads();
      // O-partial: 256 outputs (this half) x 2-lane split (32-dots)
      {
        int oi = tid >> 1, piece = tid & 1;
        int o = half*256 + oi;
        float acc = dot_f16(p.Wo + (((size_t)l*512+o)*512 + h*64) + piece*32,
                            (const ushort*)anh + piece*32, 32);
        acc += __shfl_xor(acc, 1, 64);
        if (piece == 0){
          if (h == 0) acc += xs[o] + p.sa_out_b[l*512+o];  // residual+bias once
          unsafeAtomicAdd(zb + ((size_t)t*8 + l*2)*512 + o, acc);
        }
      }
      post(t, l*2);

      // ===== stage B: LN + cross-const + LN + FF1 slice + FF2 partial =====
      float r;   // u2 (this thread's elem) for FF2 residual
      {
        float z = waitz(t, l*2, zb + ((size_t)t*8 + l*2)*512);
        float w = lnorm(z, p.ln_g + (l*3)*512, p.ln_b + (l*3)*512, nullptr, nullptr);
        float u = w + xa;
        r = lnorm(u, p.ln_g + (l*3+1)*512, p.ln_b + (l*3+1)*512, nullptr, xhh);
      }
      // FF1: 128 rows x 4-lane split (128-dots)
      {
        int row = tid >> 2, piece = tid & 3;
        float a = dot_f16(p.Wf1 + ((size_t)l*2048 + role*128 + row)*512 + piece*128,
                          (const ushort*)xhh + piece*128, 128);
        a += __shfl_xor(a, 1, 64);
        a += __shfl_xor(a, 2, 64);
        if (piece == 0)
          hsh[row] = __float2half(fmaxf(a + p.ff1_b[l*2048 + role*128 + row], 0.f));
      }
      __syncthreads();
      // FF2: 512 outputs x dot-128 over this role's hidden slice
      {
        float a0 = dot_f16(p.Wf2 + ((size_t)l*512+tid)*2048 + role*128, (const ushort*)hsh, 128);
        if (role == 0) a0 += r + p.ff2_b[l*512+tid];
        unsafeAtomicAdd(zb + ((size_t)t*8 + l*2+1)*512 + tid, a0);
      }
      post(t, l*2+1);
    } // layers

    // ===== tail: LN + mmr -> dec_out, mm -> new, se -> next emb =====
    {
      float z = waitz(t, 7, zb + ((size_t)t*8 + 7)*512);
      lnorm(z, p.ln_g + 11*512, p.ln_b + 11*512, xs, nullptr);
    }
    // mmr: 64 outs x 8-lane split (64-dots fp32)
    {
      int o8 = tid >> 3, p8 = tid & 7;
      float a = dot_f32(p.mmr_w + (size_t)o8*512 + p8*64, xs + p8*64, 64);
      a += __shfl_xor(a, 1, 64);
      a += __shfl_xor(a, 2, 64);
      a += __shfl_xor(a, 4, 64);
      if (p8 == 0) d64[o8] = a + p.mmr_b[o8];
    }
    __syncthreads();
    if (role == 0 && tid < 64) p.dec_out[((size_t)b*48+t)*64 + tid] = d64[tid];
    // mm: 512 outs x dot-64 fp32
    ns[tid] = dot_f32(p.mm_w + (size_t)tid*64, d64, 64) + p.mm_b[tid];
    __syncthreads();
    // se: 32 outs (this role) x 16-lane split (64-dots over concat[ns|sel])
    {
      int o5 = tid >> 4, p16 = tid & 15;
      int o = role*32 + o5;
      float acc = (p16 < 8)
        ? dot_f32(p.se_w + (size_t)o*1024 + p16*64, ns + p16*64, 64)
        : dot_f32(p.se_w + (size_t)o*1024 + p16*64,
                  p.sel + ((size_t)b*48+t)*512 + (p16-8)*64, 64);
      acc += __shfl_xor(acc, 1, 64);
      acc += __shfl_xor(acc, 2, 64);
      acc += __shfl_xor(acc, 4, 64);
      acc += __shfl_xor(acc, 8, 64);
      if (p16 == 0){
        acc += p.se_b[o] + p.style[(size_t)b*512+o];
        astore(p.emb + ((size_t)(t+1)*8+b)*512 + o, acc);
      }
    }
    post(t, 8);
  } // t
}

// ---------------- host ----------------
extern "C" void kernel_launch(void* const* d_in, const int* in_sizes, int n_in,
                              void* d_out, int out_size, void* d_ws, size_t ws_size,
                              hipStream_t stream){
  (void)in_sizes; (void)n_in; (void)out_size; (void)ws_size;
  const float* content = (const float*)d_in[0];
  const float* style   = (const float*)d_in[1];
  const float* shid    = (const float*)d_in[2];
  const float* init_st = (const float*)d_in[3];
  const float* ca_in_w = (const float*)d_in[4];
  const float* ca_in_b = (const float*)d_in[5];
  const float* ca_out_w= (const float*)d_in[6];
  const float* ca_out_b= (const float*)d_in[7];
  const float* se_w    = (const float*)d_in[8];
  const float* se_b    = (const float*)d_in[9];
  const float* mm_w    = (const float*)d_in[10];
  const float* mm_b    = (const float*)d_in[11];
  const float* mmr_w   = (const float*)d_in[12];
  const float* mmr_b   = (const float*)d_in[13];
  const float* sa_in_w = (const float*)d_in[14];
  const float* sa_in_b = (const float*)d_in[15];
  const float* sa_out_w= (const float*)d_in[16];
  const float* sa_out_b= (const float*)d_in[17];
  const float* xa_in_w = (const float*)d_in[18];
  const float* xa_in_b = (const float*)d_in[19];
  const float* xa_out_w= (const float*)d_in[20];
  const float* xa_out_b= (const float*)d_in[21];
  const float* ff1_w   = (const float*)d_in[22];
  const float* ff1_b   = (const float*)d_in[23];
  const float* ff2_w   = (const float*)d_in[24];
  const float* ff2_b   = (const float*)d_in[25];
  const float* ln_g    = (const float*)d_in[26];
  const float* ln_b    = (const float*)d_in[27];

  float* out = (float*)d_out;
  float* dec_out = out;            // (8,48,64)
  float* sel = out + 8*48*64;      // (8,48,512)

  char* base = (char*)d_ws;
  size_t cur = 0;
  auto alloc = [&](size_t bytes)->char*{
    char* pt = base + cur;
    cur += (bytes + 255) & ~(size_t)255;
    return pt;
  };
  // --- contiguous zero-init region: counters | z accum | emb slots ---
  unsigned* fl  = (unsigned*)alloc((size_t)8*48*9*16*4);          // 221184 B
  float* zacc   = (float*)alloc((size_t)8*48*8*512*4);            // 6.29 MB
  float* emb    = (float*)alloc((size_t)49*8*512*4);              // 0.80 MB
  size_t zero_span = cur;                                          // from fl
  // --- rest of workspace ---
  ushort* WqkvH = (ushort*)alloc((size_t)4*1536*512*2);
  ushort* WoH   = (ushort*)alloc((size_t)4*512*512*2);
  ushort* Wf1H  = (ushort*)alloc((size_t)4*2048*512*2);
  ushort* Wf2H  = (ushort*)alloc((size_t)4*512*2048*2);
  float* Wt_mm    = (float*)alloc((size_t)64*512*4);
  float* Wt_se    = (float*)alloc((size_t)1024*512*4);
  float* Wt_ca_in = (float*)alloc((size_t)512*1536*4);
  float* Wt_ca_out= (float*)alloc((size_t)512*512*4);
  float* Wt_xa_v  = (float*)alloc((size_t)4*512*512*4);
  float* Wt_xa_o  = (float*)alloc((size_t)4*512*512*4);
  float* xa_c  = (float*)alloc((size_t)4*384*512*4);
  float* pe    = (float*)alloc((size_t)48*512*4);
  float* qh    = (float*)alloc((size_t)384*512*4);
  float* khb   = (float*)alloc((size_t)512*512*4);   // K then V: adjacent
  float* vhb   = (float*)alloc((size_t)512*512*4);
  float* attno = (float*)alloc((size_t)384*512*4);
  float* xtmp4 = (float*)alloc((size_t)4*384*512*4);
  float* catb  = (float*)alloc((size_t)8*1024*4);
  float* embt  = (float*)alloc((size_t)8*512*4);
  (void)vhb;

  hipMemsetAsync(fl, 0, zero_span, stream);

  dim3 tb(32,8);
  // f16 casts (original [out][in] layout, contiguous rows)
  k_casthf<<<(4*1536*512+255)/256, 256, 0, stream>>>(sa_in_w, (__half*)WqkvH, 4*1536*512);
  k_casthf<<<(4*512*512+255)/256, 256, 0, stream>>>(sa_out_w, (__half*)WoH,  4*512*512);
  k_casthf<<<(4*2048*512+255)/256, 256, 0, stream>>>(ff1_w,  (__half*)Wf1H, 4*2048*512);
  k_casthf<<<(4*512*2048+255)/256, 256, 0, stream>>>(ff2_w,  (__half*)Wf2H, 4*512*2048);
  // fp32 transposes for the precompute GEMMs
  for (int l=0; l<4; ++l){
    k_transpose<<<dim3(16,16), tb, 0, stream>>>(xa_in_w + (size_t)l*1536*512 + (size_t)1024*512, Wt_xa_v + (size_t)l*512*512, 512, 512);
    k_transpose<<<dim3(16,16), tb, 0, stream>>>(xa_out_w + (size_t)l*512*512, Wt_xa_o + (size_t)l*512*512, 512, 512);
  }
  k_transpose<<<dim3(16,48), tb, 0, stream>>>(ca_in_w,  Wt_ca_in, 1536, 512);
  k_transpose<<<dim3(16,16), tb, 0, stream>>>(ca_out_w, Wt_ca_out, 512, 512);
  k_transpose<<<dim3(32,16), tb, 0, stream>>>(se_w,  Wt_se, 512, 1024);
  k_transpose<<<dim3(2,16),  tb, 0, stream>>>(mm_w,  Wt_mm, 512, 64);

  k_pe<<<96, 256, 0, stream>>>(pe);

  // sel = MHA(content, style_hiddens, style_hiddens), nh=1
  k_linear<<<dim3(4,48), 256, 0, stream>>>(content, 512, Wt_ca_in, 1536, ca_in_b, qh, 512, 512, 512, 0,0,0,0);
  // K and V batched (z=0:K, z=1:V)
  k_linear<<<dim3(4,64,2), 256, 0, stream>>>(shid, 512, Wt_ca_in + 512, 1536, ca_in_b + 512, khb, 512, 512, 512,
                                             0, 512, 512, (size_t)512*512);
  k_sel_attn<<<384, 256, 0, stream>>>(qh, khb, vhb, attno);
  k_linear<<<dim3(4,48), 256, 0, stream>>>(attno, 512, Wt_ca_out, 512, ca_out_b, sel, 512, 512, 512, 0,0,0,0);

  // cross-attn constants (diagonal mask -> one-hot softmax), z-batched over l
  k_linear<<<dim3(4,48,4), 256, 0, stream>>>(content, 512, Wt_xa_v, 512, xa_in_b + 1024, xtmp4, 512, 512, 512,
                                             0, (size_t)512*512, 1536, (size_t)384*512);
  k_linear<<<dim3(4,48,4), 256, 0, stream>>>(xtmp4, 512, Wt_xa_o, 512, xa_out_b, xa_c, 512, 512, 512,
                                             (size_t)384*512, (size_t)512*512, 512, (size_t)384*512);

  // emb slot 0
  k_linear<<<dim3(4,1), 256, 0, stream>>>(init_st, 64, Wt_mm, 512, mm_b, catb, 1024, 512, 64, 0,0,0,0);
  k_cat_tail<<<16, 256, 0, stream>>>(sel, catb);
  k_linear<<<dim3(4,1), 256, 0, stream>>>(catb, 1024, Wt_se, 512, se_b, embt, 512, 512, 1024, 0,0,0,0);
  k_add_style<<<16, 256, 0, stream>>>(embt, style, emb);

  DP p;
  p.fl = fl; p.z = zacc; p.emb = emb;
  p.Wqkv = WqkvH; p.Wo = WoH; p.Wf1 = Wf1H; p.Wf2 = Wf2H;
  p.xa_c = xa_c; p.pe = pe;
  p.sa_in_b = sa_in_b; p.sa_out_b = sa_out_b; p.ff1_b = ff1_b; p.ff2_b = ff2_b;
  p.mmr_w = mmr_w; p.mmr_b = mmr_b; p.mm_w = mm_w; p.mm_b = mm_b;
  p.se_w = se_w; p.se_b = se_b; p.ln_g = ln_g; p.ln_b = ln_b;
  p.style = style; p.sel = sel; p.dec_out = dec_out;

  k_decode<<<dim3(128), dim3(512), 0, stream>>>(p);
}